// Round 1
// baseline (161.535 us; speedup 1.0000x reference)
//
#include <hip/hip_runtime.h>

// Problem dims
#define B_    2
#define NCAM_ 6
#define J_    23
#define HM_   160
#define W_    640
#define H_    512
#define D_    50

static constexpr long long HF_SIZE = (long long)B_ * J_ * D_ * D_ * D_;        // 5,750,000
static constexpr long long HP_SIZE = (long long)B_ * NCAM_ * J_ * H_ * W_;     // 90,439,680
static constexpr int NBJ = B_ * J_;                                            // 46
static constexpr int CHUNKS = 32;

// ---------------------------------------------------------------------------
// Kernel A: write heatmaps_padded (zeros + placed crops), float4-vectorized
// ---------------------------------------------------------------------------
__global__ void pad_kernel(const float* __restrict__ hm_batch,
                           const int* __restrict__ centerHM,
                           float* __restrict__ out_pad) {
    const long long total4 = HP_SIZE / 4;          // 22,609,920
    const int W4 = W_ / 4;
    for (long long v = blockIdx.x * (long long)blockDim.x + threadIdx.x;
         v < total4;
         v += (long long)gridDim.x * blockDim.x) {
        long long rest = v;
        const int x4  = (int)(rest % W4); rest /= W4;
        const int y   = (int)(rest % H_); rest /= H_;
        const int j   = (int)(rest % J_); rest /= J_;
        const int cam = (int)(rest % NCAM_); rest /= NCAM_;
        const int b   = (int)rest;

        const int cx = centerHM[(b * NCAM_ + cam) * 2 + 0];
        const int cy = centerHM[(b * NCAM_ + cam) * 2 + 1];
        int x0 = cx / 2 - HM_ / 2;
        int y0 = cy / 2 - HM_ / 2;
        // dynamic_update_slice clamping semantics (inputs guarantee in-bounds,
        // but clamp is cheap and exact)
        x0 = min(max(x0, 0), W_ - HM_);
        y0 = min(max(y0, 0), H_ - HM_);

        float vals[4] = {0.f, 0.f, 0.f, 0.f};
        const int dy = y - y0;
        if (dy >= 0 && dy < HM_) {
            const float* __restrict__ src =
                hm_batch + (((long long)(b * NCAM_ + cam) * J_ + j) * HM_ + dy) * (long long)HM_;
            const int xbase = x4 * 4;
            #pragma unroll
            for (int k = 0; k < 4; ++k) {
                const int dx = xbase + k - x0;
                if (dx >= 0 && dx < HM_) vals[k] = src[dx];
            }
        }
        float4 out = make_float4(vals[0], vals[1], vals[2], vals[3]);
        reinterpret_cast<float4*>(out_pad)[v] = out;
    }
}

// ---------------------------------------------------------------------------
// Kernel B: softplus(heatmap_vol) -> out, fused 4-way reduction per (b,j)
// ---------------------------------------------------------------------------
__global__ void softplus_reduce(const float* __restrict__ vol,
                                float* __restrict__ out_hf,
                                float* __restrict__ acc) {
    const int NE = D_ * D_ * D_;                   // 125,000
    const int gid = blockIdx.x;
    const int bj = gid / CHUNKS;
    const int chunk = gid % CHUNKS;
    const long long base = (long long)bj * NE;

    float s = 0.f, sx = 0.f, sy = 0.f, sz = 0.f;
    for (int i = chunk * blockDim.x + threadIdx.x; i < NE; i += CHUNKS * blockDim.x) {
        const float x = vol[base + i];
        // softplus = logaddexp(x, 0) = max(x,0) + log1p(exp(-|x|))
        const float sp = fmaxf(x, 0.f) + log1pf(__expf(-fabsf(x)));
        out_hf[base + i] = sp;
        const int zz = i % D_;
        const int t  = i / D_;
        const int yy = t % D_;
        const int xx = t / D_;
        s  += sp;
        sx += sp * (float)xx;
        sy += sp * (float)yy;
        sz += sp * (float)zz;
    }

    // 64-lane wave reduction
    #pragma unroll
    for (int off = 32; off > 0; off >>= 1) {
        s  += __shfl_down(s,  off, 64);
        sx += __shfl_down(sx, off, 64);
        sy += __shfl_down(sy, off, 64);
        sz += __shfl_down(sz, off, 64);
    }
    __shared__ float sm[4][8];
    const int lane = threadIdx.x & 63;
    const int wid  = threadIdx.x >> 6;
    if (lane == 0) {
        sm[0][wid] = s; sm[1][wid] = sx; sm[2][wid] = sy; sm[3][wid] = sz;
    }
    __syncthreads();
    if (threadIdx.x == 0) {
        const int nw = blockDim.x >> 6;
        float a0 = 0.f, a1 = 0.f, a2 = 0.f, a3 = 0.f;
        for (int w = 0; w < nw; ++w) {
            a0 += sm[0][w]; a1 += sm[1][w]; a2 += sm[2][w]; a3 += sm[3][w];
        }
        atomicAdd(&acc[bj * 4 + 0], a0);
        atomicAdd(&acc[bj * 4 + 1], a1);
        atomicAdd(&acc[bj * 4 + 2], a2);
        atomicAdd(&acc[bj * 4 + 3], a3);
    }
}

// ---------------------------------------------------------------------------
// Kernel C: finalize points3D
// ---------------------------------------------------------------------------
__global__ void finalize_points(const float* __restrict__ acc,
                                const float* __restrict__ c3d,
                                float* __restrict__ out_p3d) {
    const int bj = threadIdx.x;
    if (bj < NBJ) {
        const int b = bj / J_;
        const float norm = acc[bj * 4 + 0];
        const float inv = 1.0f / norm;
        #pragma unroll
        for (int k = 0; k < 3; ++k) {
            const float m = acc[bj * 4 + 1 + k] * inv;
            // p * GRID_SPACING*2 - GRID_SIZE/GRID_SPACING + center3D
            out_p3d[bj * 3 + k] = m * 4.0f - 100.0f + c3d[b * 3 + k];
        }
    }
}

extern "C" void kernel_launch(void* const* d_in, const int* in_sizes, int n_in,
                              void* d_out, int out_size, void* d_ws, size_t ws_size,
                              hipStream_t stream) {
    const float* hm_batch  = (const float*)d_in[0];   // [B,NCAM,J,HM,HM]
    const float* vol       = (const float*)d_in[1];   // [B,J,D,D,D]
    const float* c3d       = (const float*)d_in[2];   // [B,1,3]
    const int*   centerHM  = (const int*)d_in[3];     // [B,NCAM,2]

    float* out     = (float*)d_out;
    float* out_hf  = out;                              // heatmap_final
    float* out_pad = out + HF_SIZE;                    // heatmaps_padded
    float* out_p3d = out + HF_SIZE + HP_SIZE;          // points3D

    float* acc = (float*)d_ws;                         // [NBJ*4] accumulators

    hipMemsetAsync(acc, 0, NBJ * 4 * sizeof(float), stream);

    softplus_reduce<<<NBJ * CHUNKS, 256, 0, stream>>>(vol, out_hf, acc);
    pad_kernel<<<8192, 256, 0, stream>>>(hm_batch, centerHM, out_pad);
    finalize_points<<<1, 64, 0, stream>>>(acc, c3d, out_p3d);
}

// Round 2
// 125.370 us; speedup vs baseline: 1.2885x; 1.2885x over previous
//
#include <hip/hip_runtime.h>

// Problem dims
#define B_    2
#define NCAM_ 6
#define J_    23
#define HM_   160
#define W_    640
#define H_    512
#define D_    50

static constexpr long long HF_SIZE = (long long)B_ * J_ * D_ * D_ * D_;        // 5,750,000
static constexpr long long HP_SIZE = (long long)B_ * NCAM_ * J_ * H_ * W_;     // 90,439,680
static constexpr int NBJ = B_ * J_;                                            // 46
static constexpr int CHUNKS = 32;
static constexpr int NPLANES = B_ * NCAM_ * J_;                                // 276
static constexpr int PLANE_F4 = (H_ * W_) / 4;                                 // 81,920 float4/plane
static constexpr int W4 = W_ / 4;                                              // 160
static constexpr int PAD_BLOCKS_X = 80;                                        // 80*256*4 = 81,920

// ---------------------------------------------------------------------------
// Kernel A: write heatmaps_padded. 2D grid: y = plane (b,cam,j), x = chunk.
// All plane-level address math is block-uniform (scalar regs). Per-thread
// math is one 32-bit div by 160 (magic-mul). Also folds the points3D
// finalize into block (0,0) — stream order guarantees acc is complete.
// ---------------------------------------------------------------------------
__global__ void pad_kernel(const float* __restrict__ hm_batch,
                           const int* __restrict__ centerHM,
                           float* __restrict__ out_pad,
                           const float* __restrict__ acc,
                           const float* __restrict__ c3d,
                           float* __restrict__ out_p3d) {
    // folded finalize: 46 threads of block (0,0)
    if (blockIdx.x == 0 && blockIdx.y == 0 && threadIdx.x < NBJ) {
        const int bj = threadIdx.x;
        const int b = bj / J_;
        const float inv = 1.0f / acc[bj * 4 + 0];
        #pragma unroll
        for (int k = 0; k < 3; ++k) {
            const float m = acc[bj * 4 + 1 + k] * inv;
            out_p3d[bj * 3 + k] = m * 4.0f - 100.0f + c3d[b * 3 + k];
        }
    }

    const int plane = blockIdx.y;                    // (b*NCAM + cam)*J + j
    const int bcam  = plane / J_;                    // b*NCAM + cam  (scalar)

    const int cx = centerHM[bcam * 2 + 0];
    const int cy = centerHM[bcam * 2 + 1];
    int x0 = cx / 2 - HM_ / 2;
    int y0 = cy / 2 - HM_ / 2;
    x0 = min(max(x0, 0), W_ - HM_);
    y0 = min(max(y0, 0), H_ - HM_);

    const float* __restrict__ src   = hm_batch + (long long)plane * (HM_ * HM_);
    float4* __restrict__ outp = reinterpret_cast<float4*>(out_pad) + (long long)plane * PLANE_F4;

    for (int f = blockIdx.x * blockDim.x + threadIdx.x; f < PLANE_F4;
         f += PAD_BLOCKS_X * blockDim.x) {
        const int y  = f / W4;                       // u32 magic-mul
        const int x4 = f - y * W4;
        float4 v = make_float4(0.f, 0.f, 0.f, 0.f);
        const int dy = y - y0;
        if (dy >= 0 && dy < HM_) {
            const float* __restrict__ row = src + dy * HM_;
            const int dxb = x4 * 4 - x0;
            float* vp = &v.x;
            #pragma unroll
            for (int k = 0; k < 4; ++k) {
                const int dx = dxb + k;
                if (dx >= 0 && dx < HM_) vp[k] = row[dx];
            }
        }
        outp[f] = v;
    }
}

// ---------------------------------------------------------------------------
// Kernel B: softplus(heatmap_vol) -> out (float4), fused 4-way reduction
// ---------------------------------------------------------------------------
__global__ void softplus_reduce(const float4* __restrict__ vol4,
                                float4* __restrict__ out4,
                                float* __restrict__ acc) {
    const int NE4 = (D_ * D_ * D_) / 4;              // 31,250
    const int gid = blockIdx.x;
    const int bj = gid / CHUNKS;
    const int chunk = gid % CHUNKS;
    const long long base4 = (long long)bj * NE4;

    float s = 0.f, sx = 0.f, sy = 0.f, sz = 0.f;
    for (int i = chunk * blockDim.x + threadIdx.x; i < NE4; i += CHUNKS * blockDim.x) {
        const float4 v = vol4[base4 + i];
        float4 sp;
        sp.x = fmaxf(v.x, 0.f) + log1pf(__expf(-fabsf(v.x)));
        sp.y = fmaxf(v.y, 0.f) + log1pf(__expf(-fabsf(v.y)));
        sp.z = fmaxf(v.z, 0.f) + log1pf(__expf(-fabsf(v.z)));
        sp.w = fmaxf(v.w, 0.f) + log1pf(__expf(-fabsf(v.w)));
        out4[base4 + i] = sp;
        const int e0 = i * 4;
        const float* spp = &sp.x;
        #pragma unroll
        for (int k = 0; k < 4; ++k) {
            const int e  = e0 + k;
            const int zz = e % D_;                   // u32 magic-mul
            const int t  = e / D_;
            const int yy = t % D_;
            const int xx = t / D_;
            const float p = spp[k];
            s  += p;
            sx += p * (float)xx;
            sy += p * (float)yy;
            sz += p * (float)zz;
        }
    }

    #pragma unroll
    for (int off = 32; off > 0; off >>= 1) {
        s  += __shfl_down(s,  off, 64);
        sx += __shfl_down(sx, off, 64);
        sy += __shfl_down(sy, off, 64);
        sz += __shfl_down(sz, off, 64);
    }
    __shared__ float sm[4][8];
    const int lane = threadIdx.x & 63;
    const int wid  = threadIdx.x >> 6;
    if (lane == 0) {
        sm[0][wid] = s; sm[1][wid] = sx; sm[2][wid] = sy; sm[3][wid] = sz;
    }
    __syncthreads();
    if (threadIdx.x == 0) {
        const int nw = blockDim.x >> 6;
        float a0 = 0.f, a1 = 0.f, a2 = 0.f, a3 = 0.f;
        for (int w = 0; w < nw; ++w) {
            a0 += sm[0][w]; a1 += sm[1][w]; a2 += sm[2][w]; a3 += sm[3][w];
        }
        atomicAdd(&acc[bj * 4 + 0], a0);
        atomicAdd(&acc[bj * 4 + 1], a1);
        atomicAdd(&acc[bj * 4 + 2], a2);
        atomicAdd(&acc[bj * 4 + 3], a3);
    }
}

extern "C" void kernel_launch(void* const* d_in, const int* in_sizes, int n_in,
                              void* d_out, int out_size, void* d_ws, size_t ws_size,
                              hipStream_t stream) {
    const float* hm_batch  = (const float*)d_in[0];   // [B,NCAM,J,HM,HM]
    const float* vol       = (const float*)d_in[1];   // [B,J,D,D,D]
    const float* c3d       = (const float*)d_in[2];   // [B,1,3]
    const int*   centerHM  = (const int*)d_in[3];     // [B,NCAM,2]

    float* out     = (float*)d_out;
    float* out_hf  = out;                              // heatmap_final
    float* out_pad = out + HF_SIZE;                    // heatmaps_padded
    float* out_p3d = out + HF_SIZE + HP_SIZE;          // points3D

    float* acc = (float*)d_ws;                         // [NBJ*4] accumulators

    hipMemsetAsync(acc, 0, NBJ * 4 * sizeof(float), stream);

    softplus_reduce<<<NBJ * CHUNKS, 256, 0, stream>>>(
        (const float4*)vol, (float4*)out_hf, acc);

    dim3 pad_grid(PAD_BLOCKS_X, NPLANES);
    pad_kernel<<<pad_grid, 256, 0, stream>>>(hm_batch, centerHM, out_pad,
                                             acc, c3d, out_p3d);
}

// Round 3
// 99.633 us; speedup vs baseline: 1.6213x; 1.2583x over previous
//
#include <hip/hip_runtime.h>

// Problem dims
#define B_    2
#define NCAM_ 6
#define J_    23
#define HM_   160
#define W_    640
#define H_    512
#define D_    50

static constexpr long long HF_SIZE = (long long)B_ * J_ * D_ * D_ * D_;        // 5,750,000
static constexpr long long HP_SIZE = (long long)B_ * NCAM_ * J_ * H_ * W_;     // 90,439,680
static constexpr int NBJ = B_ * J_;                                            // 46
static constexpr int CHUNKS = 32;
static constexpr int SP_BLOCKS = NBJ * CHUNKS;                                 // 1472
static constexpr int ZERO_BLOCKS = 4096;
static constexpr int NPLANES = B_ * NCAM_ * J_;                                // 276
static constexpr int CROP_BLOCKS = 4096;

// ---------------------------------------------------------------------------
// Kernel 1: blocks [0,SP_BLOCKS) = softplus+reduce (partials -> ws, no atomics)
//           blocks [SP_BLOCKS, SP_BLOCKS+ZERO_BLOCKS) = pure float4 zero-fill
//           of heatmaps_padded. Both memory-bound; they overlap on-chip.
// ---------------------------------------------------------------------------
__global__ void fused1(const float4* __restrict__ vol4,
                       float4* __restrict__ out_hf4,
                       float* __restrict__ partials,
                       float4* __restrict__ out_pad4) {
    const int gid = blockIdx.x;
    if (gid < SP_BLOCKS) {
        // ---- softplus + 4-way reduction ----
        const int NE4 = (D_ * D_ * D_) / 4;              // 31,250
        const int bj = gid / CHUNKS;
        const int chunk = gid % CHUNKS;
        const long long base4 = (long long)bj * NE4;

        float s = 0.f, sx = 0.f, sy = 0.f, sz = 0.f;
        for (int i = chunk * blockDim.x + threadIdx.x; i < NE4; i += CHUNKS * blockDim.x) {
            const float4 v = vol4[base4 + i];
            float4 sp;
            sp.x = fmaxf(v.x, 0.f) + log1pf(__expf(-fabsf(v.x)));
            sp.y = fmaxf(v.y, 0.f) + log1pf(__expf(-fabsf(v.y)));
            sp.z = fmaxf(v.z, 0.f) + log1pf(__expf(-fabsf(v.z)));
            sp.w = fmaxf(v.w, 0.f) + log1pf(__expf(-fabsf(v.w)));
            out_hf4[base4 + i] = sp;
            const int e0 = i * 4;
            const float* spp = &sp.x;
            #pragma unroll
            for (int k = 0; k < 4; ++k) {
                const int e  = e0 + k;
                const int zz = e % D_;                   // u32 magic-mul
                const int t  = e / D_;
                const int yy = t % D_;
                const int xx = t / D_;
                const float p = spp[k];
                s  += p;
                sx += p * (float)xx;
                sy += p * (float)yy;
                sz += p * (float)zz;
            }
        }

        #pragma unroll
        for (int off = 32; off > 0; off >>= 1) {
            s  += __shfl_down(s,  off, 64);
            sx += __shfl_down(sx, off, 64);
            sy += __shfl_down(sy, off, 64);
            sz += __shfl_down(sz, off, 64);
        }
        __shared__ float sm[4][4];
        const int lane = threadIdx.x & 63;
        const int wid  = threadIdx.x >> 6;
        if (lane == 0) {
            sm[0][wid] = s; sm[1][wid] = sx; sm[2][wid] = sy; sm[3][wid] = sz;
        }
        __syncthreads();
        if (threadIdx.x == 0) {
            float a0 = 0.f, a1 = 0.f, a2 = 0.f, a3 = 0.f;
            #pragma unroll
            for (int w = 0; w < 4; ++w) {
                a0 += sm[0][w]; a1 += sm[1][w]; a2 += sm[2][w]; a3 += sm[3][w];
            }
            partials[gid * 4 + 0] = a0;
            partials[gid * 4 + 1] = a1;
            partials[gid * 4 + 2] = a2;
            partials[gid * 4 + 3] = a3;
        }
    } else {
        // ---- branch-free zero fill of heatmaps_padded ----
        const long long n4 = HP_SIZE / 4;                // 22,609,920
        const int zb = gid - SP_BLOCKS;
        const float4 z = make_float4(0.f, 0.f, 0.f, 0.f);
        for (long long i = (long long)zb * blockDim.x + threadIdx.x; i < n4;
             i += (long long)ZERO_BLOCKS * blockDim.x) {
            out_pad4[i] = z;
        }
    }
}

// ---------------------------------------------------------------------------
// Kernel 2: copy crops over the zeros (float4) + finalize points3D (block 0)
// ---------------------------------------------------------------------------
__global__ void crop_finalize(const float4* __restrict__ hm4,
                              const int* __restrict__ centerHM,
                              float* __restrict__ out_pad,
                              const float* __restrict__ partials,
                              const float* __restrict__ c3d,
                              float* __restrict__ out_p3d) {
    if (blockIdx.x == 0 && threadIdx.x < NBJ) {
        const int bj = threadIdx.x;
        const int b = bj / J_;
        float a0 = 0.f, a1 = 0.f, a2 = 0.f, a3 = 0.f;
        for (int c = 0; c < CHUNKS; ++c) {
            const float* p = &partials[(bj * CHUNKS + c) * 4];
            a0 += p[0]; a1 += p[1]; a2 += p[2]; a3 += p[3];
        }
        const float inv = 1.0f / a0;
        out_p3d[bj * 3 + 0] = a1 * inv * 4.0f - 100.0f + c3d[b * 3 + 0];
        out_p3d[bj * 3 + 1] = a2 * inv * 4.0f - 100.0f + c3d[b * 3 + 1];
        out_p3d[bj * 3 + 2] = a3 * inv * 4.0f - 100.0f + c3d[b * 3 + 2];
    }

    const int HM4 = HM_ / 4;                             // 40 float4 per crop row
    const int PLANE4 = HM_ * HM4;                        // 6400 float4 per crop
    const int total4 = NPLANES * PLANE4;                 // 1,766,400
    for (int i = blockIdx.x * blockDim.x + threadIdx.x; i < total4;
         i += CROP_BLOCKS * blockDim.x) {
        const int plane = i / PLANE4;                    // u32 magic-mul
        const int rem   = i - plane * PLANE4;
        const int dy    = rem / HM4;
        const int dx4   = rem - dy * HM4;
        const int bcam  = plane / J_;

        const int cx = centerHM[bcam * 2 + 0];
        const int cy = centerHM[bcam * 2 + 1];
        int x0 = cx / 2 - HM_ / 2;
        int y0 = cy / 2 - HM_ / 2;
        x0 = min(max(x0, 0), W_ - HM_);
        y0 = min(max(y0, 0), H_ - HM_);

        const float4 v = hm4[i];
        float* dst = out_pad + (long long)plane * (H_ * W_)
                   + (y0 + dy) * W_ + x0 + dx4 * 4;
        *reinterpret_cast<float4*>(dst) = v;             // 4B-aligned dwordx4 ok
    }
}

extern "C" void kernel_launch(void* const* d_in, const int* in_sizes, int n_in,
                              void* d_out, int out_size, void* d_ws, size_t ws_size,
                              hipStream_t stream) {
    const float* hm_batch  = (const float*)d_in[0];   // [B,NCAM,J,HM,HM]
    const float* vol       = (const float*)d_in[1];   // [B,J,D,D,D]
    const float* c3d       = (const float*)d_in[2];   // [B,1,3]
    const int*   centerHM  = (const int*)d_in[3];     // [B,NCAM,2]

    float* out     = (float*)d_out;
    float* out_hf  = out;                              // heatmap_final
    float* out_pad = out + HF_SIZE;                    // heatmaps_padded
    float* out_p3d = out + HF_SIZE + HP_SIZE;          // points3D

    float* partials = (float*)d_ws;                    // [SP_BLOCKS*4]

    fused1<<<SP_BLOCKS + ZERO_BLOCKS, 256, 0, stream>>>(
        (const float4*)vol, (float4*)out_hf, partials, (float4*)out_pad);

    crop_finalize<<<CROP_BLOCKS, 256, 0, stream>>>(
        (const float4*)hm_batch, centerHM, out_pad, partials, c3d, out_p3d);
}